// Round 1
// baseline (1856.591 us; speedup 1.0000x reference)
//
#include <hip/hip_runtime.h>

#define DCH 128

struct Pairs {
  const float* A[4];
  const float* W[4];
  const int*   idx[4];
};

// ---------------- CSR build ----------------

__global__ void hist2_kernel(const int* __restrict__ gi_src, const int* __restrict__ gu_src,
                             int* __restrict__ deg_gi, int* __restrict__ deg_gu,
                             int egi, int egu) {
  int t = blockIdx.x * blockDim.x + threadIdx.x;
  if (t < egi) atomicAdd(&deg_gi[gi_src[t]], 1);
  int u = t - egi;
  if (u >= 0 && u < egu) atomicAdd(&deg_gu[gu_src[u]], 1);
}

__global__ __launch_bounds__(1024) void scan2_kernel(
    const int* __restrict__ degA, int* __restrict__ offA, int* __restrict__ curA,
    const int* __restrict__ degB, int* __restrict__ offB, int* __restrict__ curB, int n) {
  const int* deg = blockIdx.x ? degB : degA;
  int* off = blockIdx.x ? offB : offA;
  int* cur = blockIdx.x ? curB : curA;
  __shared__ int part[1024];
  int t = threadIdx.x;
  int per = (n + 1023) >> 10;
  int start = min(t * per, n);
  int end = min(start + per, n);
  int s = 0;
  for (int i = start; i < end; ++i) s += deg[i];
  part[t] = s;
  __syncthreads();
  for (int dstep = 1; dstep < 1024; dstep <<= 1) {
    int v = (t >= dstep) ? part[t - dstep] : 0;
    __syncthreads();
    part[t] += v;
    __syncthreads();
  }
  int excl = (t == 0) ? 0 : part[t - 1];
  for (int i = start; i < end; ++i) { off[i] = excl; cur[i] = excl; excl += deg[i]; }
  if (end == n) off[n] = excl;
}

__global__ void fill2_kernel(const int* __restrict__ gi_src, const int* __restrict__ gi_dst,
                             const int* __restrict__ gu_src, const int* __restrict__ gu_dst,
                             int* __restrict__ cur_gi, int* __restrict__ col_gi,
                             int* __restrict__ cur_gu, int* __restrict__ col_gu,
                             int egi, int egu) {
  int t = blockIdx.x * blockDim.x + threadIdx.x;
  if (t < egi) {
    int p = atomicAdd(&cur_gi[gi_src[t]], 1);
    col_gi[p] = gi_dst[t];
  }
  int u = t - egi;
  if (u >= 0 && u < egu) {
    int p = atomicAdd(&cur_gu[gu_src[u]], 1);
    col_gu[p] = gu_dst[u];
  }
}

// ---------------- segment mean over CSR ----------------
// one block (128 threads) per group; thread d accumulates channel d.
__global__ void agg_mean_kernel(const float* __restrict__ feat, const int* __restrict__ idx,
                                const int* __restrict__ off, const int* __restrict__ col,
                                float* __restrict__ out) {
  int g = blockIdx.x;
  int d = threadIdx.x;
  int s = off[g], e = off[g + 1];
  float acc = 0.f;
  for (int j = s; j < e; ++j) {
    int c = col[j];
    if (idx) c = idx[c];
    acc += feat[(size_t)c * DCH + d];
  }
  out[(size_t)g * DCH + d] = acc * (1.0f / (float)max(e - s, 1));
}

// ---------------- Y[Mx128] = relu( sum_p A_p @ W_p + ba + bb ) ----------------
// BM=64, N=128 fixed, K=128 per pair staged in BK=32 chunks.
// 256 threads: tx in [0,32) -> 4 cols, ty in [0,8) -> 8 rows. 32 acc/thread.
__global__ __launch_bounds__(256) void gemm128_relu_kernel(
    Pairs pr, int npairs, const float* __restrict__ ba, const float* __restrict__ bb,
    float* __restrict__ Y, int M) {
  __shared__ float AsT[32][64];   // [k][m]
  __shared__ float Ws[32][DCH];   // [k][n]
  int m0 = blockIdx.x * 64;
  int tx = threadIdx.x & 31;
  int ty = threadIdx.x >> 5;
  float acc[8][4];
#pragma unroll
  for (int i = 0; i < 8; ++i)
#pragma unroll
    for (int j = 0; j < 4; ++j) acc[i][j] = 0.f;

  for (int p = 0; p < npairs; ++p) {
    const float* A = pr.A[p];
    const float* W = pr.W[p];
    const int* idx = pr.idx[p];
    for (int k0 = 0; k0 < DCH; k0 += 32) {
      // stage A tile (64 rows x 32 k), transposed into AsT[k][m]
      {
        int r = threadIdx.x >> 3;
        int kp = (threadIdx.x & 7) * 4;
#pragma unroll
        for (int pass = 0; pass < 2; ++pass, r += 32) {
          int m = m0 + r;
          float4 v = make_float4(0.f, 0.f, 0.f, 0.f);
          if (m < M) {
            int row = idx ? idx[m] : m;
            v = *(const float4*)(A + (size_t)row * DCH + k0 + kp);
          }
          AsT[kp + 0][r] = v.x; AsT[kp + 1][r] = v.y;
          AsT[kp + 2][r] = v.z; AsT[kp + 3][r] = v.w;
        }
      }
      // stage W chunk (32 k-rows x 128 cols)
      {
        int kk = threadIdx.x >> 5;
        int c4 = (threadIdx.x & 31) * 4;
#pragma unroll
        for (int pass = 0; pass < 4; ++pass, kk += 8) {
          *(float4*)&Ws[kk][c4] = *(const float4*)(W + (size_t)(k0 + kk) * DCH + c4);
        }
      }
      __syncthreads();
#pragma unroll
      for (int k = 0; k < 32; ++k) {
        float4 b = *(const float4*)&Ws[k][tx * 4];
        float4 a0 = *(const float4*)&AsT[k][ty * 8];
        float4 a1 = *(const float4*)&AsT[k][ty * 8 + 4];
        float av[8] = {a0.x, a0.y, a0.z, a0.w, a1.x, a1.y, a1.z, a1.w};
#pragma unroll
        for (int i = 0; i < 8; ++i) {
          acc[i][0] = fmaf(av[i], b.x, acc[i][0]);
          acc[i][1] = fmaf(av[i], b.y, acc[i][1]);
          acc[i][2] = fmaf(av[i], b.z, acc[i][2]);
          acc[i][3] = fmaf(av[i], b.w, acc[i][3]);
        }
      }
      __syncthreads();
    }
  }
  float4 bias = make_float4(0.f, 0.f, 0.f, 0.f);
  if (ba) {
    float4 v = *(const float4*)(ba + tx * 4);
    bias.x += v.x; bias.y += v.y; bias.z += v.z; bias.w += v.w;
  }
  if (bb) {
    float4 v = *(const float4*)(bb + tx * 4);
    bias.x += v.x; bias.y += v.y; bias.z += v.z; bias.w += v.w;
  }
#pragma unroll
  for (int i = 0; i < 8; ++i) {
    int m = m0 + ty * 8 + i;
    if (m < M) {
      float4 o;
      o.x = fmaxf(acc[i][0] + bias.x, 0.f);
      o.y = fmaxf(acc[i][1] + bias.y, 0.f);
      o.z = fmaxf(acc[i][2] + bias.z, 0.f);
      o.w = fmaxf(acc[i][3] + bias.w, 0.f);
      *(float4*)(Y + (size_t)m * DCH + tx * 4) = o;
    }
  }
}

// ---------------- out[MxN] = A[Mx128] @ B[128xN] + bias[N] ----------------
// 64x64 tile, 256 threads, 4x4 micro-tile per thread, BK=32.
__global__ __launch_bounds__(256) void final_gemm_kernel(
    const float* __restrict__ A, const float* __restrict__ B,
    const float* __restrict__ bias, float* __restrict__ Y, int M, int N) {
  __shared__ float AsT[32][64];   // [k][m]
  __shared__ float Bs[32][64];    // [k][n]
  int n0 = blockIdx.x * 64;
  int m0 = blockIdx.y * 64;
  int tx = threadIdx.x & 15;   // cols tx*4..+3
  int ty = threadIdx.x >> 4;   // rows ty*4..+3
  float acc[4][4];
#pragma unroll
  for (int i = 0; i < 4; ++i)
#pragma unroll
    for (int j = 0; j < 4; ++j) acc[i][j] = 0.f;

  for (int k0 = 0; k0 < DCH; k0 += 32) {
    {
      int r = threadIdx.x >> 3;
      int kp = (threadIdx.x & 7) * 4;
#pragma unroll
      for (int pass = 0; pass < 2; ++pass, r += 32) {
        int m = m0 + r;
        float4 v = make_float4(0.f, 0.f, 0.f, 0.f);
        if (m < M) v = *(const float4*)(A + (size_t)m * DCH + k0 + kp);
        AsT[kp + 0][r] = v.x; AsT[kp + 1][r] = v.y;
        AsT[kp + 2][r] = v.z; AsT[kp + 3][r] = v.w;
      }
    }
    {
      int k = threadIdx.x >> 4;          // 0..15
      int c4 = (threadIdx.x & 15) * 4;
#pragma unroll
      for (int pass = 0; pass < 2; ++pass, k += 16) {
        int n = n0 + c4;
        float4 v = make_float4(0.f, 0.f, 0.f, 0.f);
        if (n < N) v = *(const float4*)(B + (size_t)(k0 + k) * N + n);
        *(float4*)&Bs[k][c4] = v;
      }
    }
    __syncthreads();
#pragma unroll
    for (int kk = 0; kk < 32; ++kk) {
      float4 a = *(const float4*)&AsT[kk][ty * 4];
      float4 b = *(const float4*)&Bs[kk][tx * 4];
      acc[0][0] = fmaf(a.x, b.x, acc[0][0]); acc[0][1] = fmaf(a.x, b.y, acc[0][1]);
      acc[0][2] = fmaf(a.x, b.z, acc[0][2]); acc[0][3] = fmaf(a.x, b.w, acc[0][3]);
      acc[1][0] = fmaf(a.y, b.x, acc[1][0]); acc[1][1] = fmaf(a.y, b.y, acc[1][1]);
      acc[1][2] = fmaf(a.y, b.z, acc[1][2]); acc[1][3] = fmaf(a.y, b.w, acc[1][3]);
      acc[2][0] = fmaf(a.z, b.x, acc[2][0]); acc[2][1] = fmaf(a.z, b.y, acc[2][1]);
      acc[2][2] = fmaf(a.z, b.z, acc[2][2]); acc[2][3] = fmaf(a.z, b.w, acc[2][3]);
      acc[3][0] = fmaf(a.w, b.x, acc[3][0]); acc[3][1] = fmaf(a.w, b.y, acc[3][1]);
      acc[3][2] = fmaf(a.w, b.z, acc[3][2]); acc[3][3] = fmaf(a.w, b.w, acc[3][3]);
    }
    __syncthreads();
  }
  int n = n0 + tx * 4;
  if (n < N) {
    float4 bv = *(const float4*)(bias + n);
#pragma unroll
    for (int i = 0; i < 4; ++i) {
      int m = m0 + ty * 4 + i;
      if (m < M) {
        float4 o = make_float4(acc[i][0] + bv.x, acc[i][1] + bv.y,
                               acc[i][2] + bv.z, acc[i][3] + bv.w);
        *(float4*)(Y + (size_t)m * N + n) = o;
      }
    }
  }
}

extern "C" void kernel_launch(void* const* d_in, const int* in_sizes, int n_in,
                              void* d_out, int out_size, void* d_ws, size_t ws_size,
                              hipStream_t stream) {
  const int* x_user = (const int*)d_in[1];
  const int* x_item = (const int*)d_in[2];
  const int* gi_src = (const int*)d_in[3];
  const int* gi_dst = (const int*)d_in[4];
  const int* gu_src = (const int*)d_in[5];
  const int* gu_dst = (const int*)d_in[6];
  const float* emb_user = (const float*)d_in[8];
  const float* emb_item = (const float*)d_in[9];
  const float* Wl1 = (const float*)d_in[10];
  const float* Wr1 = (const float*)d_in[11];
  const float* b1  = (const float*)d_in[12];
  const float* Wl2 = (const float*)d_in[13];
  const float* Wr2 = (const float*)d_in[14];
  const float* b2  = (const float*)d_in[15];
  const float* Wp  = (const float*)d_in[16];
  const float* bp  = (const float*)d_in[17];

  const int NG = in_sizes[0], NU = in_sizes[1], NI = in_sizes[2];
  const int EGI = in_sizes[3], EGU = in_sizes[5];
  const int DD = DCH * DCH;

  // ---- workspace carve (~35 MB) ----
  char* w = (char*)d_ws;
  auto carve = [&](size_t bytes) {
    char* p = w;
    w += (bytes + 255) & ~(size_t)255;
    return p;
  };
  int* deg_gi = (int*)carve((size_t)NG * 4);
  int* deg_gu = (int*)carve((size_t)NG * 4);
  int* off_gi = (int*)carve((size_t)(NG + 1) * 4);
  int* off_gu = (int*)carve((size_t)(NG + 1) * 4);
  int* cur_gi = (int*)carve((size_t)NG * 4);
  int* cur_gu = (int*)carve((size_t)NG * 4);
  int* col_gi = (int*)carve((size_t)EGI * 4);
  int* col_gu = (int*)carve((size_t)EGU * 4);
  float* A_I  = (float*)carve((size_t)NG * DCH * 4);
  float* A_U  = (float*)carve((size_t)NG * DCH * 4);
  float* g1   = (float*)carve((size_t)NG * DCH * 4);
  float* A_I2 = (float*)carve((size_t)NG * DCH * 4);
  float* A_U2 = (float*)carve((size_t)NG * DCH * 4);
  float* g2   = (float*)carve((size_t)NG * DCH * 4);
  // big activations live in d_out (dead before final GEMM overwrites it)
  float* u1 = (float*)d_out;                      // NU x 128
  float* i1 = (float*)d_out + (size_t)NU * DCH;   // NI x 128

  hipMemsetAsync(deg_gi, 0, (size_t)NG * 4, stream);
  hipMemsetAsync(deg_gu, 0, (size_t)NG * 4, stream);

  int etot = EGI + EGU;
  hist2_kernel<<<(etot + 255) / 256, 256, 0, stream>>>(gi_src, gu_src, deg_gi, deg_gu, EGI, EGU);
  scan2_kernel<<<2, 1024, 0, stream>>>(deg_gi, off_gi, cur_gi, deg_gu, off_gu, cur_gu, NG);
  fill2_kernel<<<(etot + 255) / 256, 256, 0, stream>>>(gi_src, gi_dst, gu_src, gu_dst,
                                                       cur_gi, col_gi, cur_gu, col_gu, EGI, EGU);

  // layer-1 neighbor means onto groups
  agg_mean_kernel<<<NG, DCH, 0, stream>>>(emb_item, x_item, off_gi, col_gi, A_I);
  agg_mean_kernel<<<NG, DCH, 0, stream>>>(emb_user, x_user, off_gu, col_gu, A_U);

  // i1 = relu(hi @ Wr1[0] + b1[0]);  u1 = relu(hu @ Wr1[2] + b1[2])
  {
    Pairs pr{};
    pr.A[0] = emb_item; pr.W[0] = Wr1 + 0 * DD; pr.idx[0] = x_item;
    gemm128_relu_kernel<<<(NI + 63) / 64, 256, 0, stream>>>(pr, 1, b1 + 0 * DCH, nullptr, i1, NI);
  }
  {
    Pairs pr{};
    pr.A[0] = emb_user; pr.W[0] = Wr1 + 2 * DD; pr.idx[0] = x_user;
    gemm128_relu_kernel<<<(NU + 63) / 64, 256, 0, stream>>>(pr, 1, b1 + 2 * DCH, nullptr, u1, NU);
  }
  // g1 = relu(A_I @ Wl1[1] + A_U @ Wl1[3] + b1[1] + b1[3])
  {
    Pairs pr{};
    pr.A[0] = A_I; pr.W[0] = Wl1 + 1 * DD;
    pr.A[1] = A_U; pr.W[1] = Wl1 + 3 * DD;
    gemm128_relu_kernel<<<(NG + 63) / 64, 256, 0, stream>>>(pr, 2, b1 + 1 * DCH, b1 + 3 * DCH, g1, NG);
  }
  // layer-2 neighbor means onto groups
  agg_mean_kernel<<<NG, DCH, 0, stream>>>(i1, nullptr, off_gi, col_gi, A_I2);
  agg_mean_kernel<<<NG, DCH, 0, stream>>>(u1, nullptr, off_gu, col_gu, A_U2);

  // g2 = relu(A_I2@Wl2[1] + A_U2@Wl2[3] + g1@Wr2[1] + g1@Wr2[3] + b2[1] + b2[3])
  {
    Pairs pr{};
    pr.A[0] = A_I2; pr.W[0] = Wl2 + 1 * DD;
    pr.A[1] = A_U2; pr.W[1] = Wl2 + 3 * DD;
    pr.A[2] = g1;   pr.W[2] = Wr2 + 1 * DD;
    pr.A[3] = g1;   pr.W[3] = Wr2 + 3 * DD;
    gemm128_relu_kernel<<<(NG + 63) / 64, 256, 0, stream>>>(pr, 4, b2 + 1 * DCH, b2 + 3 * DCH, g2, NG);
  }

  // out = g2 @ Wp + bp
  dim3 fgrid((unsigned)((NI + 63) / 64), (unsigned)((NG + 63) / 64));
  final_gemm_kernel<<<fgrid, 256, 0, stream>>>(g2, Wp, bp, (float*)d_out, NG, NI);
}